// Round 7
// baseline (115.245 us; speedup 1.0000x reference)
//
#include <hip/hip_runtime.h>
#include <math.h>

#define NG 4096
#define WI 80
#define HI 80
#define NPIX (WI*HI)
#define FOCAL 40.0f
#define LIM 1.3f
#define CAP 1536

#define SH_C0 0.28209479177387814f
#define SH_C1 0.4886025119029199f

// ws byte layout:
//  U0 @ 0      : float4[NG] {gx,gy,rcx,rcy}   (unsorted)
//  U1 @ 64KB   : float4[NG] {ca,cb,cc,op}
//  U2 @ 128KB  : float4[NG] {r,g,b,0}
//  S0 @ 192KB  : float4[NG] sorted {gx,gy,rcx,rcy}
//  B1 @ 256KB  : float4[NG] sorted {gx,gy,ca,cb}
//  B2 @ 320KB  : float4[NG] sorted {cc,op,r,g}
//  B3 @ 384KB  : float [NG] sorted {b}
//  KD @ 400KB  : u64  [NG] key = depth_bits<<32 | i
//  RK @ 432KB  : int  [NG] rank (zeroed by prep)
#define U0_OFF 0
#define U1_OFF (64*1024)
#define U2_OFF (128*1024)
#define S0_OFF (192*1024)
#define B1_OFF (256*1024)
#define B2_OFF (320*1024)
#define B3_OFF (384*1024)
#define KD_OFF (400*1024)
#define RK_OFF (432*1024)

__global__ __launch_bounds__(256) void prep_k(
    const float* __restrict__ means, const float* __restrict__ sh,
    const int* __restrict__ shidx, const int* __restrict__ gidx,
    const float* __restrict__ opac, const float* __restrict__ scales,
    const float* __restrict__ sfac, const float* __restrict__ rots,
    const float* __restrict__ ext, char* __restrict__ wsb,
    float* __restrict__ radii_out)
{
  int i = blockIdx.x*blockDim.x + threadIdx.x;
  if (i >= NG) return;
  float e0=ext[0],  e1=ext[1],  e2=ext[2];
  float e4=ext[4],  e5=ext[5],  e6=ext[6];
  float e8=ext[8],  e9=ext[9],  e10=ext[10];
  float e12=ext[12], e13=ext[13], e14=ext[14];
  float m0=means[3*i+0], m1=means[3*i+1], m2=means[3*i+2];
  float tx = m0*e0 + m1*e4 + m2*e8  + e12;
  float ty = m0*e1 + m1*e5 + m2*e9  + e13;
  float tz = m0*e2 + m1*e6 + m2*e10 + e14;
  bool infront = tz > 0.2f;
  float tzs = infront ? tz : 1.0f;
  float inv_tzs = 1.0f / tzs;
  float gx = ((tx*inv_tzs + 1.0f)*WI - 1.0f)*0.5f;
  float gy = ((ty*inv_tzs + 1.0f)*HI - 1.0f)*0.5f;

  int gi = gidx[i];
  float sf = sfac[i];
  float s0 = scales[3*gi+0]*sf, s1 = scales[3*gi+1]*sf, s2 = scales[3*gi+2]*sf;
  float qw = rots[4*gi+0], qx = rots[4*gi+1], qy = rots[4*gi+2], qz = rots[4*gi+3];
  float qinv = rsqrtf(qw*qw+qx*qx+qy*qy+qz*qz);
  qw*=qinv; qx*=qinv; qy*=qinv; qz*=qinv;
  float r00 = 1.0f - 2.0f*(qy*qy+qz*qz);
  float r01 = 2.0f*(qx*qy - qw*qz);
  float r02 = 2.0f*(qx*qz + qw*qy);
  float r10 = 2.0f*(qx*qy + qw*qz);
  float r11 = 1.0f - 2.0f*(qx*qx+qz*qz);
  float r12 = 2.0f*(qy*qz - qw*qx);
  float r20 = 2.0f*(qx*qz - qw*qy);
  float r21 = 2.0f*(qy*qz + qw*qx);
  float r22 = 1.0f - 2.0f*(qx*qx+qy*qy);
  float v0 = s0*s0, v1 = s1*s1, v2 = s2*s2;
  float C00 = r00*r00*v0 + r01*r01*v1 + r02*r02*v2;
  float C01 = r00*r10*v0 + r01*r11*v1 + r02*r12*v2;
  float C02 = r00*r20*v0 + r01*r21*v1 + r02*r22*v2;
  float C11 = r10*r10*v0 + r11*r11*v1 + r12*r12*v2;
  float C12 = r10*r20*v0 + r11*r21*v1 + r12*r22*v2;
  float C22 = r20*r20*v0 + r21*r21*v1 + r22*r22*v2;
  float W0x=e0, W0y=e4, W0z=e8;
  float W1x=e1, W1y=e5, W1z=e9;
  float W2x=e2, W2y=e6, W2z=e10;
  float B00 = W0x*C00 + W0y*C01 + W0z*C02;
  float B01 = W0x*C01 + W0y*C11 + W0z*C12;
  float B02 = W0x*C02 + W0y*C12 + W0z*C22;
  float B10 = W1x*C00 + W1y*C01 + W1z*C02;
  float B11 = W1x*C01 + W1y*C11 + W1z*C12;
  float B12 = W1x*C02 + W1y*C12 + W1z*C22;
  float B20 = W2x*C00 + W2y*C01 + W2z*C02;
  float B21 = W2x*C01 + W2y*C11 + W2z*C12;
  float B22 = W2x*C02 + W2y*C12 + W2z*C22;
  float V00 = B00*W0x + B01*W0y + B02*W0z;
  float V02 = B00*W2x + B01*W2y + B02*W2z;
  float V01 = B00*W1x + B01*W1y + B02*W1z;
  float V11 = B10*W1x + B11*W1y + B12*W1z;
  float V12 = B10*W2x + B11*W2y + B12*W2z;
  float V22 = B20*W2x + B21*W2y + B22*W2z;
  float txz = tx*inv_tzs, tyz = ty*inv_tzs;
  float txc = fminf(fmaxf(txz, -LIM), LIM) * tzs;
  float tyc = fminf(fmaxf(tyz, -LIM), LIM) * tzs;
  float jx  = FOCAL*inv_tzs;
  float jy  = FOCAL*inv_tzs;
  float jz0 = -FOCAL*txc*inv_tzs*inv_tzs;
  float jz1 = -FOCAL*tyc*inv_tzs*inv_tzs;
  float c00 = jx*jx*V00 + 2.0f*jx*jz0*V02 + jz0*jz0*V22;
  float c01 = jx*jy*V01 + jx*jz1*V02 + jz0*jy*V12 + jz0*jz1*V22;
  float c11 = jy*jy*V11 + 2.0f*jy*jz1*V12 + jz1*jz1*V22;
  float a = c00 + 0.3f;
  float b = c01;
  float cf = c11 + 0.3f;
  float det = a*cf - b*b;
  bool valid = infront && (det > 0.0f);
  float dets = (det != 0.0f) ? det : 1.0f;
  float ca = cf/dets, cb = -b/dets, cc = a/dets;
  float mid = 0.5f*(a+cf);
  float lam1 = mid + sqrtf(fmaxf(0.1f, mid*mid - det));
  float radf = valid ? ceilf(3.0f*sqrtf(lam1)) : 0.0f;
  radii_out[i] = radf;

  float op = valid ? opac[i] : 0.0f;
  // Exact per-axis bbox of {alpha >= 1/255}: half-widths sqrt(2L*a), sqrt(2L*c)
  float L2 = 2.0f*fmaxf(0.0f, logf(255.0f*op));
  float rcx = valid ? sqrtf(L2*a)  + 0.01f : 0.0f;
  float rcy = valid ? sqrtf(L2*cf) + 0.01f : 0.0f;

  float cp0 = -(e12*e0 + e13*e1 + e14*e2);
  float cp1 = -(e12*e4 + e13*e5 + e14*e6);
  float cp2 = -(e12*e8 + e13*e9 + e14*e10);
  float dx0 = m0-cp0, dy0 = m1-cp1, dz0 = m2-cp2;
  float dn = rsqrtf(dx0*dx0+dy0*dy0+dz0*dz0);
  float x = dx0*dn, y = dy0*dn, z = dz0*dn;
  float xx=x*x, yy=y*y, zz=z*z;
  float xy=x*y, yz=y*z, xz=x*z;
  float bf[16];
  bf[0]  = SH_C0;
  bf[1]  = -SH_C1*y;
  bf[2]  =  SH_C1*z;
  bf[3]  = -SH_C1*x;
  bf[4]  =  1.0925484305920792f*xy;
  bf[5]  = -1.0925484305920792f*yz;
  bf[6]  =  0.31539156525252005f*(2.0f*zz-xx-yy);
  bf[7]  = -1.0925484305920792f*xz;
  bf[8]  =  0.5462742152960396f*(xx-yy);
  bf[9]  = -0.5900435899266435f*y*(3.0f*xx-yy);
  bf[10] =  2.890611442640554f*xy*z;
  bf[11] = -0.4570457994644658f*y*(4.0f*zz-xx-yy);
  bf[12] =  0.3731763325901154f*z*(2.0f*zz-3.0f*xx-3.0f*yy);
  bf[13] = -0.4570457994644658f*x*(4.0f*zz-xx-yy);
  bf[14] =  1.445305721320277f*z*(xx-yy);
  bf[15] = -0.5900435899266435f*x*(xx-yy-3.0f*zz);
  const float* S = sh + (long)shidx[i]*48;
  float cr=0.f, cg=0.f, cbl=0.f;
  #pragma unroll
  for (int j=0;j<16;j++) {
    float w = bf[j];
    cr  += w*S[j*3+0];
    cg  += w*S[j*3+1];
    cbl += w*S[j*3+2];
  }
  cr  = fmaxf(cr +0.5f, 0.0f);
  cg  = fmaxf(cg +0.5f, 0.0f);
  cbl = fmaxf(cbl+0.5f, 0.0f);

  float depth = infront ? tz : __builtin_inff();
  ((float4*)(wsb + U0_OFF))[i] = make_float4(gx, gy, rcx, rcy);
  ((float4*)(wsb + U1_OFF))[i] = make_float4(ca, cb, cc, op);
  ((float4*)(wsb + U2_OFF))[i] = make_float4(cr, cg, cbl, 0.0f);
  ((unsigned long long*)(wsb + KD_OFF))[i] =
      ((unsigned long long)__float_as_uint(depth) << 32) | (unsigned)i;
  ((int*)(wsb + RK_OFF))[i] = 0;
}

// Global stable rank: rotation-offset reads -> lane-parallel coalesced, VALU compares.
__global__ __launch_bounds__(256) void rank_k(const char* __restrict__ wsb,
                                              int* __restrict__ rank)
{
  const unsigned long long* kd = (const unsigned long long*)(wsb + KD_OFF);
  int tid = threadIdx.x;
  int i = blockIdx.x*256 + tid;
  unsigned long long ki = kd[i];
  int jb = blockIdx.y*256;
  int r = 0;
  #pragma unroll 8
  for (int jj = 0; jj < 256; ++jj) {
    unsigned long long kj = kd[jb + ((tid + jj) & 255)];
    r += (kj < ki);
  }
  atomicAdd(&rank[i], r);
}

__global__ __launch_bounds__(256) void scatter_k(char* __restrict__ wsb)
{
  int i = blockIdx.x*256 + threadIdx.x;
  int r = ((const int*)(wsb + RK_OFF))[i];
  float4 u0 = ((const float4*)(wsb + U0_OFF))[i];
  float4 u1 = ((const float4*)(wsb + U1_OFF))[i];
  float4 u2 = ((const float4*)(wsb + U2_OFF))[i];
  ((float4*)(wsb + S0_OFF))[r] = u0;
  ((float4*)(wsb + B1_OFF))[r] = make_float4(u0.x, u0.y, u1.x, u1.y);
  ((float4*)(wsb + B2_OFF))[r] = make_float4(u1.z, u1.w, u2.x, u2.y);
  ((float*) (wsb + B3_OFF))[r] = u2.z;
}

// tile_k: one block per 8x8 tile, 512 threads (8 waves).
// A: stream SORTED cull array, order-preserving compaction (popcount + LDS
//    wave-prefix, 1 barrier/chunk via parity double-buffer) -> sidx in depth order.
// B: 8-way segment blend; sidx prefetched to registers (shfl broadcast),
//    params via wave-uniform global loads (vector pipe / L1), no LDS in loop.
__global__ __launch_bounds__(512) void tile_k(const char* __restrict__ wsb,
                                              const float* __restrict__ bg,
                                              float* __restrict__ out)
{
  __shared__ int sidx[CAP];
  __shared__ int wcnt[2][8];
  __shared__ float pT[8][64], pR[8][64], pG[8][64], pB[8][64];
  const float4* S0 = (const float4*)(wsb + S0_OFF);
  const float4* B1 = (const float4*)(wsb + B1_OFF);
  const float4* B2 = (const float4*)(wsb + B2_OFF);
  const float*  B3 = (const float*) (wsb + B3_OFF);

  int tid = threadIdx.x;
  int wv = tid >> 6, lane = tid & 63;
  int tile = blockIdx.x;
  int x0 = (tile % 10) * 8, y0 = (tile / 10) * 8;
  float bx0 = (float)x0, bx1 = (float)(x0+7);
  float by0 = (float)y0, by1 = (float)(y0+7);

  int scnt = 0;  // wave-uniform running total (all threads track same value)
  for (int c = 0; c < NG/512; ++c) {
    int i = c*512 + tid;
    float4 v = S0[i];                       // gx, gy, rcx, rcy (sorted)
    bool hit = (v.z > 0.0f) &&
               (v.x + v.z >= bx0) && (v.x - v.z <= bx1) &&
               (v.y + v.w >= by0) && (v.y - v.w <= by1);
    unsigned long long m = __ballot(hit);
    int par = c & 1;
    if (lane == 0) wcnt[par][wv] = __popcll(m);
    __syncthreads();
    int pre = 0, tot = 0;
    #pragma unroll
    for (int w = 0; w < 8; ++w) {
      int cw = wcnt[par][w];
      pre += (w < wv) ? cw : 0;
      tot += cw;
    }
    if (hit) {
      int pos = scnt + pre + __popcll(m & ((1ull<<lane)-1ull));
      if (pos < CAP) sidx[pos] = i;
    }
    scnt += tot;
  }
  __syncthreads();
  int cnt = scnt; if (cnt > CAP) cnt = CAP;

  // blend: 8 segments x 64 lanes(=pixels)
  float px = (float)(x0 + (lane & 7));
  float py = (float)(y0 + (lane >> 3));
  int seg = (cnt + 7) >> 3;
  int s0i = wv*seg;
  int s1i = s0i + seg; if (s1i > cnt) s1i = cnt;
  float T = 1.0f, ar = 0.f, ag = 0.f, ab = 0.f;
  for (int eb = s0i; eb < s1i; eb += 64) {
    int nn = s1i - eb; if (nn > 64) nn = 64;
    int myidx = (lane < nn) ? sidx[eb + lane] : 0;   // lane-parallel LDS read
    for (int c16 = 0; c16 < nn && __ballot(T >= 1e-4f); c16 += 16) {
      int ce = c16 + 16; if (ce > nn) ce = nn;
      #pragma unroll 4
      for (int e = c16; e < ce; ++e) {
        int g = __shfl(myidx, e, 64);                // register broadcast
        float4 q1 = B1[g];   // gx,gy,ca,cb
        float4 q2 = B2[g];   // cc,op,r,g
        float  b3 = B3[g];
        float dx = q1.x - px, dy = q1.y - py;
        float power = -0.5f*(q1.z*dx*dx + q2.x*dy*dy) - q1.w*dx*dy;
        float al = 0.0f;
        if (power <= 0.0f) {
          float av = fminf(0.99f, q2.y*__expf(power));
          if (av >= (1.0f/255.0f)) al = av;
        }
        float w = al*T;
        ar += w*q2.z; ag += w*q2.w; ab += w*b3;
        T *= 1.0f - al;
      }
    }
  }
  pT[wv][lane]=T; pR[wv][lane]=ar; pG[wv][lane]=ag; pB[wv][lane]=ab;
  __syncthreads();

  if (tid < 64) {
    float Tg = 1.0f, r = 0.f, g2 = 0.f, b2 = 0.f;
    #pragma unroll
    for (int w = 0; w < 8; ++w) {
      r  += Tg*pR[w][tid];
      g2 += Tg*pG[w][tid];
      b2 += Tg*pB[w][tid];
      Tg *= pT[w][tid];
    }
    int p = (y0 + (tid>>3))*WI + (x0 + (tid&7));
    out[0*NPIX+p] = r  + Tg*bg[0];
    out[1*NPIX+p] = g2 + Tg*bg[1];
    out[2*NPIX+p] = b2 + Tg*bg[2];
  }
}

extern "C" void kernel_launch(void* const* d_in, const int* in_sizes, int n_in,
                              void* d_out, int out_size, void* d_ws, size_t ws_size,
                              hipStream_t stream) {
  const float* means  = (const float*)d_in[0];
  const float* sh     = (const float*)d_in[1];
  const int*   shidx  = (const int*)  d_in[2];
  const int*   gidx   = (const int*)  d_in[3];
  const float* opac   = (const float*)d_in[4];
  const float* scales = (const float*)d_in[5];
  const float* sfac   = (const float*)d_in[6];
  const float* rots   = (const float*)d_in[7];
  const float* ext    = (const float*)d_in[8];
  const float* bg     = (const float*)d_in[9];
  float* out = (float*)d_out;
  char* wsb = (char*)d_ws;

  prep_k<<<NG/256, 256, 0, stream>>>(means, sh, shidx, gidx, opac, scales, sfac,
                                     rots, ext, wsb, out + 3*NPIX);
  dim3 rg(NG/256, NG/256);
  rank_k<<<rg, 256, 0, stream>>>(wsb, (int*)(wsb + RK_OFF));
  scatter_k<<<NG/256, 256, 0, stream>>>(wsb);
  tile_k<<<100, 512, 0, stream>>>(wsb, bg, out);
}

// Round 8
// 96.126 us; speedup vs baseline: 1.1989x; 1.1989x over previous
//
#include <hip/hip_runtime.h>
#include <math.h>

#define NG 4096
#define WI 80
#define HI 80
#define NPIX (WI*HI)
#define FOCAL 40.0f
#define LIM 1.3f
#define CAP 1536

#define SH_C0 0.28209479177387814f
#define SH_C1 0.4886025119029199f

// ws byte layout:
//  U0 @ 0      : float4[NG] {gx,gy,rcx,rcy}   (unsorted)
//  U1 @ 64KB   : float4[NG] {ca,cb,cc,op}
//  U2 @ 128KB  : float4[NG] {r,g,b,0}
//  S0 @ 192KB  : float4[NG] sorted {gx,gy,rcx,rcy}
//  B1 @ 256KB  : float4[NG] sorted {gx,gy,ca,cb}
//  B2 @ 320KB  : float4[NG] sorted {cc,op,r,g}
//  B3 @ 384KB  : float [NG] sorted {b}
//  KD @ 400KB  : u64  [NG] key = depth_bits<<32 | i
//  RK @ 432KB  : int  [NG] rank (zeroed by prep)
#define U0_OFF 0
#define U1_OFF (64*1024)
#define U2_OFF (128*1024)
#define S0_OFF (192*1024)
#define B1_OFF (256*1024)
#define B2_OFF (320*1024)
#define B3_OFF (384*1024)
#define KD_OFF (400*1024)
#define RK_OFF (432*1024)

__global__ __launch_bounds__(256) void prep_k(
    const float* __restrict__ means, const float* __restrict__ sh,
    const int* __restrict__ shidx, const int* __restrict__ gidx,
    const float* __restrict__ opac, const float* __restrict__ scales,
    const float* __restrict__ sfac, const float* __restrict__ rots,
    const float* __restrict__ ext, char* __restrict__ wsb,
    float* __restrict__ radii_out)
{
  int i = blockIdx.x*blockDim.x + threadIdx.x;
  if (i >= NG) return;
  float e0=ext[0],  e1=ext[1],  e2=ext[2];
  float e4=ext[4],  e5=ext[5],  e6=ext[6];
  float e8=ext[8],  e9=ext[9],  e10=ext[10];
  float e12=ext[12], e13=ext[13], e14=ext[14];
  float m0=means[3*i+0], m1=means[3*i+1], m2=means[3*i+2];
  float tx = m0*e0 + m1*e4 + m2*e8  + e12;
  float ty = m0*e1 + m1*e5 + m2*e9  + e13;
  float tz = m0*e2 + m1*e6 + m2*e10 + e14;
  bool infront = tz > 0.2f;
  float tzs = infront ? tz : 1.0f;
  float inv_tzs = 1.0f / tzs;
  float gx = ((tx*inv_tzs + 1.0f)*WI - 1.0f)*0.5f;
  float gy = ((ty*inv_tzs + 1.0f)*HI - 1.0f)*0.5f;

  int gi = gidx[i];
  float sf = sfac[i];
  float s0 = scales[3*gi+0]*sf, s1 = scales[3*gi+1]*sf, s2 = scales[3*gi+2]*sf;
  float qw = rots[4*gi+0], qx = rots[4*gi+1], qy = rots[4*gi+2], qz = rots[4*gi+3];
  float qinv = rsqrtf(qw*qw+qx*qx+qy*qy+qz*qz);
  qw*=qinv; qx*=qinv; qy*=qinv; qz*=qinv;
  float r00 = 1.0f - 2.0f*(qy*qy+qz*qz);
  float r01 = 2.0f*(qx*qy - qw*qz);
  float r02 = 2.0f*(qx*qz + qw*qy);
  float r10 = 2.0f*(qx*qy + qw*qz);
  float r11 = 1.0f - 2.0f*(qx*qx+qz*qz);
  float r12 = 2.0f*(qy*qz - qw*qx);
  float r20 = 2.0f*(qx*qz - qw*qy);
  float r21 = 2.0f*(qy*qz + qw*qx);
  float r22 = 1.0f - 2.0f*(qx*qx+qy*qy);
  float v0 = s0*s0, v1 = s1*s1, v2 = s2*s2;
  float C00 = r00*r00*v0 + r01*r01*v1 + r02*r02*v2;
  float C01 = r00*r10*v0 + r01*r11*v1 + r02*r12*v2;
  float C02 = r00*r20*v0 + r01*r21*v1 + r02*r22*v2;
  float C11 = r10*r10*v0 + r11*r11*v1 + r12*r12*v2;
  float C12 = r10*r20*v0 + r11*r21*v1 + r12*r22*v2;
  float C22 = r20*r20*v0 + r21*r21*v1 + r22*r22*v2;
  float W0x=e0, W0y=e4, W0z=e8;
  float W1x=e1, W1y=e5, W1z=e9;
  float W2x=e2, W2y=e6, W2z=e10;
  float B00 = W0x*C00 + W0y*C01 + W0z*C02;
  float B01 = W0x*C01 + W0y*C11 + W0z*C12;
  float B02 = W0x*C02 + W0y*C12 + W0z*C22;
  float B10 = W1x*C00 + W1y*C01 + W1z*C02;
  float B11 = W1x*C01 + W1y*C11 + W1z*C12;
  float B12 = W1x*C02 + W1y*C12 + W1z*C22;
  float B20 = W2x*C00 + W2y*C01 + W2z*C02;
  float B21 = W2x*C01 + W2y*C11 + W2z*C12;
  float B22 = W2x*C02 + W2y*C12 + W2z*C22;
  float V00 = B00*W0x + B01*W0y + B02*W0z;
  float V02 = B00*W2x + B01*W2y + B02*W2z;
  float V01 = B00*W1x + B01*W1y + B02*W1z;
  float V11 = B10*W1x + B11*W1y + B12*W1z;
  float V12 = B10*W2x + B11*W2y + B12*W2z;
  float V22 = B20*W2x + B21*W2y + B22*W2z;
  float txz = tx*inv_tzs, tyz = ty*inv_tzs;
  float txc = fminf(fmaxf(txz, -LIM), LIM) * tzs;
  float tyc = fminf(fmaxf(tyz, -LIM), LIM) * tzs;
  float jx  = FOCAL*inv_tzs;
  float jy  = FOCAL*inv_tzs;
  float jz0 = -FOCAL*txc*inv_tzs*inv_tzs;
  float jz1 = -FOCAL*tyc*inv_tzs*inv_tzs;
  float c00 = jx*jx*V00 + 2.0f*jx*jz0*V02 + jz0*jz0*V22;
  float c01 = jx*jy*V01 + jx*jz1*V02 + jz0*jy*V12 + jz0*jz1*V22;
  float c11 = jy*jy*V11 + 2.0f*jy*jz1*V12 + jz1*jz1*V22;
  float a = c00 + 0.3f;
  float b = c01;
  float cf = c11 + 0.3f;
  float det = a*cf - b*b;
  bool valid = infront && (det > 0.0f);
  float dets = (det != 0.0f) ? det : 1.0f;
  float ca = cf/dets, cb = -b/dets, cc = a/dets;
  float mid = 0.5f*(a+cf);
  float lam1 = mid + sqrtf(fmaxf(0.1f, mid*mid - det));
  float radf = valid ? ceilf(3.0f*sqrtf(lam1)) : 0.0f;
  radii_out[i] = radf;

  float op = valid ? opac[i] : 0.0f;
  // Exact per-axis bbox of {alpha >= 1/255}: half-widths sqrt(2L*a), sqrt(2L*c)
  float L2 = 2.0f*fmaxf(0.0f, logf(255.0f*op));
  float rcx = valid ? sqrtf(L2*a)  + 0.01f : 0.0f;
  float rcy = valid ? sqrtf(L2*cf) + 0.01f : 0.0f;

  float cp0 = -(e12*e0 + e13*e1 + e14*e2);
  float cp1 = -(e12*e4 + e13*e5 + e14*e6);
  float cp2 = -(e12*e8 + e13*e9 + e14*e10);
  float dx0 = m0-cp0, dy0 = m1-cp1, dz0 = m2-cp2;
  float dn = rsqrtf(dx0*dx0+dy0*dy0+dz0*dz0);
  float x = dx0*dn, y = dy0*dn, z = dz0*dn;
  float xx=x*x, yy=y*y, zz=z*z;
  float xy=x*y, yz=y*z, xz=x*z;
  float bf[16];
  bf[0]  = SH_C0;
  bf[1]  = -SH_C1*y;
  bf[2]  =  SH_C1*z;
  bf[3]  = -SH_C1*x;
  bf[4]  =  1.0925484305920792f*xy;
  bf[5]  = -1.0925484305920792f*yz;
  bf[6]  =  0.31539156525252005f*(2.0f*zz-xx-yy);
  bf[7]  = -1.0925484305920792f*xz;
  bf[8]  =  0.5462742152960396f*(xx-yy);
  bf[9]  = -0.5900435899266435f*y*(3.0f*xx-yy);
  bf[10] =  2.890611442640554f*xy*z;
  bf[11] = -0.4570457994644658f*y*(4.0f*zz-xx-yy);
  bf[12] =  0.3731763325901154f*z*(2.0f*zz-3.0f*xx-3.0f*yy);
  bf[13] = -0.4570457994644658f*x*(4.0f*zz-xx-yy);
  bf[14] =  1.445305721320277f*z*(xx-yy);
  bf[15] = -0.5900435899266435f*x*(xx-yy-3.0f*zz);
  const float* S = sh + (long)shidx[i]*48;
  float cr=0.f, cg=0.f, cbl=0.f;
  #pragma unroll
  for (int j=0;j<16;j++) {
    float w = bf[j];
    cr  += w*S[j*3+0];
    cg  += w*S[j*3+1];
    cbl += w*S[j*3+2];
  }
  cr  = fmaxf(cr +0.5f, 0.0f);
  cg  = fmaxf(cg +0.5f, 0.0f);
  cbl = fmaxf(cbl+0.5f, 0.0f);

  float depth = infront ? tz : __builtin_inff();
  ((float4*)(wsb + U0_OFF))[i] = make_float4(gx, gy, rcx, rcy);
  ((float4*)(wsb + U1_OFF))[i] = make_float4(ca, cb, cc, op);
  ((float4*)(wsb + U2_OFF))[i] = make_float4(cr, cg, cbl, 0.0f);
  ((unsigned long long*)(wsb + KD_OFF))[i] =
      ((unsigned long long)__float_as_uint(depth) << 32) | (unsigned)i;
  ((int*)(wsb + RK_OFF))[i] = 0;
}

// Global stable rank: rotation-offset reads -> lane-parallel coalesced, VALU compares.
__global__ __launch_bounds__(256) void rank_k(const char* __restrict__ wsb,
                                              int* __restrict__ rank)
{
  const unsigned long long* kd = (const unsigned long long*)(wsb + KD_OFF);
  int tid = threadIdx.x;
  int i = blockIdx.x*256 + tid;
  unsigned long long ki = kd[i];
  int jb = blockIdx.y*256;
  int r = 0;
  #pragma unroll 8
  for (int jj = 0; jj < 256; ++jj) {
    unsigned long long kj = kd[jb + ((tid + jj) & 255)];
    r += (kj < ki);
  }
  atomicAdd(&rank[i], r);
}

__global__ __launch_bounds__(256) void scatter_k(char* __restrict__ wsb)
{
  int i = blockIdx.x*256 + threadIdx.x;
  int r = ((const int*)(wsb + RK_OFF))[i];
  float4 u0 = ((const float4*)(wsb + U0_OFF))[i];
  float4 u1 = ((const float4*)(wsb + U1_OFF))[i];
  float4 u2 = ((const float4*)(wsb + U2_OFF))[i];
  ((float4*)(wsb + S0_OFF))[r] = u0;
  ((float4*)(wsb + B1_OFF))[r] = make_float4(u0.x, u0.y, u1.x, u1.y);
  ((float4*)(wsb + B2_OFF))[r] = make_float4(u1.z, u1.w, u2.x, u2.y);
  ((float*) (wsb + B3_OFF))[r] = u2.z;
}

// tile_k: one block per 8x8 tile, 1024 threads (16 waves).
// A: 4 chunks over SORTED cull array; order-preserving ballot compaction with
//    fused param staging: a hit thread's params live at its OWN sorted index i,
//    so it loads B1/B2/B3[i] and writes LDS[pos] directly (no sidx, no gather).
// B: 16-way segment blend from LDS (broadcast reads), unroll-4, chunked
//    early-out; front-to-back monoid combine of 16 partials.
__global__ __launch_bounds__(1024) void tile_k(const char* __restrict__ wsb,
                                               const float* __restrict__ bg,
                                               float* __restrict__ out)
{
  __shared__ float4 sb1[CAP];          // gx,gy,ca,cb
  __shared__ float4 sb2[CAP];          // cc,op,r,g
  __shared__ float  sb3[CAP];          // b
  __shared__ int    wcnt[2][16];
  __shared__ float  pT[16][64], pR[16][64], pG[16][64], pB[16][64];
  const float4* S0 = (const float4*)(wsb + S0_OFF);
  const float4* B1 = (const float4*)(wsb + B1_OFF);
  const float4* B2 = (const float4*)(wsb + B2_OFF);
  const float*  B3 = (const float*) (wsb + B3_OFF);

  int tid = threadIdx.x;
  int wv = tid >> 6, lane = tid & 63;
  int tile = blockIdx.x;
  int x0 = (tile % 10) * 8, y0 = (tile / 10) * 8;
  float bx0 = (float)x0, bx1 = (float)(x0+7);
  float by0 = (float)y0, by1 = (float)(y0+7);

  int scnt = 0;  // wave-uniform running total
  #pragma unroll
  for (int c = 0; c < NG/1024; ++c) {
    int i = c*1024 + tid;
    float4 v = S0[i];                       // gx, gy, rcx, rcy (sorted)
    bool hit = (v.z > 0.0f) &&
               (v.x + v.z >= bx0) && (v.x - v.z <= bx1) &&
               (v.y + v.w >= by0) && (v.y - v.w <= by1);
    unsigned long long m = __ballot(hit);
    int par = c & 1;
    if (lane == 0) wcnt[par][wv] = __popcll(m);
    __syncthreads();
    int pre = 0, tot = 0;
    #pragma unroll
    for (int w = 0; w < 16; ++w) {
      int cw = wcnt[par][w];
      pre += (w < wv) ? cw : 0;
      tot += cw;
    }
    if (hit) {
      int pos = scnt + pre + __popcll(m & ((1ull<<lane)-1ull));
      if (pos < CAP) {
        sb1[pos] = B1[i];
        sb2[pos] = B2[i];
        sb3[pos] = B3[i];
      }
    }
    scnt += tot;
  }
  __syncthreads();
  int cnt = (scnt > CAP) ? CAP : scnt;

  // blend: 16 segments x 64 lanes(=pixels)
  float px = (float)(x0 + (lane & 7));
  float py = (float)(y0 + (lane >> 3));
  int seg = (cnt + 15) >> 4;
  int s0i = wv*seg;
  int s1i = s0i + seg; if (s1i > cnt) s1i = cnt;
  float T = 1.0f, ar = 0.f, ag = 0.f, ab = 0.f;
  for (int c16 = s0i; c16 < s1i && __ballot(T >= 1e-4f); c16 += 16) {
    int ce = c16 + 16; if (ce > s1i) ce = s1i;
    #pragma unroll 4
    for (int e = c16; e < ce; ++e) {
      float4 q1 = sb1[e];
      float4 q2 = sb2[e];
      float  b3 = sb3[e];
      float dx = q1.x - px, dy = q1.y - py;
      float power = -0.5f*(q1.z*dx*dx + q2.x*dy*dy) - q1.w*dx*dy;
      float al = 0.0f;
      if (power <= 0.0f) {
        float av = fminf(0.99f, q2.y*__expf(power));
        if (av >= (1.0f/255.0f)) al = av;
      }
      float w = al*T;
      ar += w*q2.z; ag += w*q2.w; ab += w*b3;
      T *= 1.0f - al;
    }
  }
  pT[wv][lane]=T; pR[wv][lane]=ar; pG[wv][lane]=ag; pB[wv][lane]=ab;
  __syncthreads();

  if (tid < 64) {
    float Tg = 1.0f, r = 0.f, g2 = 0.f, b2 = 0.f;
    #pragma unroll
    for (int w = 0; w < 16; ++w) {
      r  += Tg*pR[w][tid];
      g2 += Tg*pG[w][tid];
      b2 += Tg*pB[w][tid];
      Tg *= pT[w][tid];
    }
    int p = (y0 + (tid>>3))*WI + (x0 + (tid&7));
    out[0*NPIX+p] = r  + Tg*bg[0];
    out[1*NPIX+p] = g2 + Tg*bg[1];
    out[2*NPIX+p] = b2 + Tg*bg[2];
  }
}

extern "C" void kernel_launch(void* const* d_in, const int* in_sizes, int n_in,
                              void* d_out, int out_size, void* d_ws, size_t ws_size,
                              hipStream_t stream) {
  const float* means  = (const float*)d_in[0];
  const float* sh     = (const float*)d_in[1];
  const int*   shidx  = (const int*)  d_in[2];
  const int*   gidx   = (const int*)  d_in[3];
  const float* opac   = (const float*)d_in[4];
  const float* scales = (const float*)d_in[5];
  const float* sfac   = (const float*)d_in[6];
  const float* rots   = (const float*)d_in[7];
  const float* ext    = (const float*)d_in[8];
  const float* bg     = (const float*)d_in[9];
  float* out = (float*)d_out;
  char* wsb = (char*)d_ws;

  prep_k<<<NG/256, 256, 0, stream>>>(means, sh, shidx, gidx, opac, scales, sfac,
                                     rots, ext, wsb, out + 3*NPIX);
  dim3 rg(NG/256, NG/256);
  rank_k<<<rg, 256, 0, stream>>>(wsb, (int*)(wsb + RK_OFF));
  scatter_k<<<NG/256, 256, 0, stream>>>(wsb);
  tile_k<<<100, 1024, 0, stream>>>(wsb, bg, out);
}

// Round 10
// 95.168 us; speedup vs baseline: 1.2110x; 1.0101x over previous
//
#include <hip/hip_runtime.h>
#include <math.h>

#define NG 4096
#define WI 80
#define HI 80
#define NPIX (WI*HI)
#define FOCAL 40.0f
#define LIM 1.3f
#define NPART 4
#define RANGE (NG/NPART)          // 1024 sorted ranks per part

#define SH_C0 0.28209479177387814f
#define SH_C1 0.4886025119029199f

// ws byte layout:
//  U0 @ 0      : float4[NG] {gx,gy,rcx,rcy}   (unsorted)
//  U1 @ 64KB   : float4[NG] {ca,cb,cc,op}
//  U2 @ 128KB  : float4[NG] {r,g,b,0}
//  S0 @ 192KB  : float4[NG] sorted {gx,gy,rcx,rcy}
//  B1 @ 256KB  : float4[NG] sorted {gx,gy,ca,cb}
//  B2 @ 320KB  : float4[NG] sorted {cc,op,r,g}
//  B3 @ 384KB  : float [NG] sorted {b}
//  KD @ 400KB  : u64  [NG] key = depth_bits<<32 | i
//  RK @ 432KB  : int  [NG] rank (zeroed by prep)
//  PP @ 448KB  : float4[NPART*NPIX] per-part pixel partials {T,r,g,b}
#define U0_OFF 0
#define U1_OFF (64*1024)
#define U2_OFF (128*1024)
#define S0_OFF (192*1024)
#define B1_OFF (256*1024)
#define B2_OFF (320*1024)
#define B3_OFF (384*1024)
#define KD_OFF (400*1024)
#define RK_OFF (432*1024)
#define PP_OFF (448*1024)

__device__ inline float rdlane(float v, int l) {
  return __uint_as_float(__builtin_amdgcn_readlane(__float_as_uint(v), l));
}

__global__ __launch_bounds__(256) void prep_k(
    const float* __restrict__ means, const float* __restrict__ sh,
    const int* __restrict__ shidx, const int* __restrict__ gidx,
    const float* __restrict__ opac, const float* __restrict__ scales,
    const float* __restrict__ sfac, const float* __restrict__ rots,
    const float* __restrict__ ext, char* __restrict__ wsb,
    float* __restrict__ radii_out)
{
  int i = blockIdx.x*blockDim.x + threadIdx.x;
  if (i >= NG) return;
  float e0=ext[0],  e1=ext[1],  e2=ext[2];
  float e4=ext[4],  e5=ext[5],  e6=ext[6];
  float e8=ext[8],  e9=ext[9],  e10=ext[10];
  float e12=ext[12], e13=ext[13], e14=ext[14];
  float m0=means[3*i+0], m1=means[3*i+1], m2=means[3*i+2];
  float tx = m0*e0 + m1*e4 + m2*e8  + e12;
  float ty = m0*e1 + m1*e5 + m2*e9  + e13;
  float tz = m0*e2 + m1*e6 + m2*e10 + e14;
  bool infront = tz > 0.2f;
  float tzs = infront ? tz : 1.0f;
  float inv_tzs = 1.0f / tzs;
  float gx = ((tx*inv_tzs + 1.0f)*WI - 1.0f)*0.5f;
  float gy = ((ty*inv_tzs + 1.0f)*HI - 1.0f)*0.5f;

  int gi = gidx[i];
  float sf = sfac[i];
  float s0 = scales[3*gi+0]*sf, s1 = scales[3*gi+1]*sf, s2 = scales[3*gi+2]*sf;
  float qw = rots[4*gi+0], qx = rots[4*gi+1], qy = rots[4*gi+2], qz = rots[4*gi+3];
  float qinv = rsqrtf(qw*qw+qx*qx+qy*qy+qz*qz);
  qw*=qinv; qx*=qinv; qy*=qinv; qz*=qinv;
  float r00 = 1.0f - 2.0f*(qy*qy+qz*qz);
  float r01 = 2.0f*(qx*qy - qw*qz);
  float r02 = 2.0f*(qx*qz + qw*qy);
  float r10 = 2.0f*(qx*qy + qw*qz);
  float r11 = 1.0f - 2.0f*(qx*qx+qz*qz);
  float r12 = 2.0f*(qy*qz - qw*qx);
  float r20 = 2.0f*(qx*qz - qw*qy);
  float r21 = 2.0f*(qy*qz + qw*qx);
  float r22 = 1.0f - 2.0f*(qx*qx+qy*qy);
  float v0 = s0*s0, v1 = s1*s1, v2 = s2*s2;
  float C00 = r00*r00*v0 + r01*r01*v1 + r02*r02*v2;
  float C01 = r00*r10*v0 + r01*r11*v1 + r02*r12*v2;
  float C02 = r00*r20*v0 + r01*r21*v1 + r02*r22*v2;
  float C11 = r10*r10*v0 + r11*r11*v1 + r12*r12*v2;
  float C12 = r10*r20*v0 + r11*r21*v1 + r12*r22*v2;
  float C22 = r20*r20*v0 + r21*r21*v1 + r22*r22*v2;
  float W0x=e0, W0y=e4, W0z=e8;
  float W1x=e1, W1y=e5, W1z=e9;
  float W2x=e2, W2y=e6, W2z=e10;
  float B00 = W0x*C00 + W0y*C01 + W0z*C02;
  float B01 = W0x*C01 + W0y*C11 + W0z*C12;
  float B02 = W0x*C02 + W0y*C12 + W0z*C22;
  float B10 = W1x*C00 + W1y*C01 + W1z*C02;
  float B11 = W1x*C01 + W1y*C11 + W1z*C12;
  float B12 = W1x*C02 + W1y*C12 + W1z*C22;
  float B20 = W2x*C00 + W2y*C01 + W2z*C02;
  float B21 = W2x*C01 + W2y*C11 + W2z*C12;
  float B22 = W2x*C02 + W2y*C12 + W2z*C22;
  float V00 = B00*W0x + B01*W0y + B02*W0z;
  float V02 = B00*W2x + B01*W2y + B02*W2z;
  float V01 = B00*W1x + B01*W1y + B02*W1z;
  float V11 = B10*W1x + B11*W1y + B12*W1z;
  float V12 = B10*W2x + B11*W2y + B12*W2z;
  float V22 = B20*W2x + B21*W2y + B22*W2z;
  float txz = tx*inv_tzs, tyz = ty*inv_tzs;
  float txc = fminf(fmaxf(txz, -LIM), LIM) * tzs;
  float tyc = fminf(fmaxf(tyz, -LIM), LIM) * tzs;
  float jx  = FOCAL*inv_tzs;
  float jy  = FOCAL*inv_tzs;
  float jz0 = -FOCAL*txc*inv_tzs*inv_tzs;
  float jz1 = -FOCAL*tyc*inv_tzs*inv_tzs;
  float c00 = jx*jx*V00 + 2.0f*jx*jz0*V02 + jz0*jz0*V22;
  float c01 = jx*jy*V01 + jx*jz1*V02 + jz0*jy*V12 + jz0*jz1*V22;
  float c11 = jy*jy*V11 + 2.0f*jy*jz1*V12 + jz1*jz1*V22;
  float a = c00 + 0.3f;
  float b = c01;
  float cf = c11 + 0.3f;
  float det = a*cf - b*b;
  bool valid = infront && (det > 0.0f);
  float dets = (det != 0.0f) ? det : 1.0f;
  float ca = cf/dets, cb = -b/dets, cc = a/dets;
  float mid = 0.5f*(a+cf);
  float lam1 = mid + sqrtf(fmaxf(0.1f, mid*mid - det));
  float radf = valid ? ceilf(3.0f*sqrtf(lam1)) : 0.0f;
  radii_out[i] = radf;

  float op = valid ? opac[i] : 0.0f;
  // Exact per-axis bbox of {alpha >= 1/255}: half-widths sqrt(2L*a), sqrt(2L*c)
  float L2 = 2.0f*fmaxf(0.0f, logf(255.0f*op));
  float rcx = valid ? sqrtf(L2*a)  + 0.01f : 0.0f;
  float rcy = valid ? sqrtf(L2*cf) + 0.01f : 0.0f;

  float cp0 = -(e12*e0 + e13*e1 + e14*e2);
  float cp1 = -(e12*e4 + e13*e5 + e14*e6);
  float cp2 = -(e12*e8 + e13*e9 + e14*e10);
  float dx0 = m0-cp0, dy0 = m1-cp1, dz0 = m2-cp2;
  float dn = rsqrtf(dx0*dx0+dy0*dy0+dz0*dz0);
  float x = dx0*dn, y = dy0*dn, z = dz0*dn;
  float xx=x*x, yy=y*y, zz=z*z;
  float xy=x*y, yz=y*z, xz=x*z;
  float bf[16];
  bf[0]  = SH_C0;
  bf[1]  = -SH_C1*y;
  bf[2]  =  SH_C1*z;
  bf[3]  = -SH_C1*x;
  bf[4]  =  1.0925484305920792f*xy;
  bf[5]  = -1.0925484305920792f*yz;
  bf[6]  =  0.31539156525252005f*(2.0f*zz-xx-yy);
  bf[7]  = -1.0925484305920792f*xz;
  bf[8]  =  0.5462742152960396f*(xx-yy);
  bf[9]  = -0.5900435899266435f*y*(3.0f*xx-yy);
  bf[10] =  2.890611442640554f*xy*z;
  bf[11] = -0.4570457994644658f*y*(4.0f*zz-xx-yy);
  bf[12] =  0.3731763325901154f*z*(2.0f*zz-3.0f*xx-3.0f*yy);
  bf[13] = -0.4570457994644658f*x*(4.0f*zz-xx-yy);
  bf[14] =  1.445305721320277f*z*(xx-yy);
  bf[15] = -0.5900435899266435f*x*(xx-yy-3.0f*zz);
  const float* S = sh + (long)shidx[i]*48;
  float cr=0.f, cg=0.f, cbl=0.f;
  #pragma unroll
  for (int j=0;j<16;j++) {
    float w = bf[j];
    cr  += w*S[j*3+0];
    cg  += w*S[j*3+1];
    cbl += w*S[j*3+2];
  }
  cr  = fmaxf(cr +0.5f, 0.0f);
  cg  = fmaxf(cg +0.5f, 0.0f);
  cbl = fmaxf(cbl+0.5f, 0.0f);

  float depth = infront ? tz : __builtin_inff();
  ((float4*)(wsb + U0_OFF))[i] = make_float4(gx, gy, rcx, rcy);
  ((float4*)(wsb + U1_OFF))[i] = make_float4(ca, cb, cc, op);
  ((float4*)(wsb + U2_OFF))[i] = make_float4(cr, cg, cbl, 0.0f);
  ((unsigned long long*)(wsb + KD_OFF))[i] =
      ((unsigned long long)__float_as_uint(depth) << 32) | (unsigned)i;
  ((int*)(wsb + RK_OFF))[i] = 0;
}

// Global stable rank: rotation-offset reads -> lane-parallel coalesced, VALU compares.
__global__ __launch_bounds__(256) void rank_k(const char* __restrict__ wsb,
                                              int* __restrict__ rank)
{
  const unsigned long long* kd = (const unsigned long long*)(wsb + KD_OFF);
  int tid = threadIdx.x;
  int i = blockIdx.x*256 + tid;
  unsigned long long ki = kd[i];
  int jb = blockIdx.y*256;
  int r = 0;
  #pragma unroll 8
  for (int jj = 0; jj < 256; ++jj) {
    unsigned long long kj = kd[jb + ((tid + jj) & 255)];
    r += (kj < ki);
  }
  atomicAdd(&rank[i], r);
}

__global__ __launch_bounds__(256) void scatter_k(char* __restrict__ wsb)
{
  int i = blockIdx.x*256 + threadIdx.x;
  int r = ((const int*)(wsb + RK_OFF))[i];
  float4 u0 = ((const float4*)(wsb + U0_OFF))[i];
  float4 u1 = ((const float4*)(wsb + U1_OFF))[i];
  float4 u2 = ((const float4*)(wsb + U2_OFF))[i];
  ((float4*)(wsb + S0_OFF))[r] = u0;
  ((float4*)(wsb + B1_OFF))[r] = make_float4(u0.x, u0.y, u1.x, u1.y);
  ((float4*)(wsb + B2_OFF))[r] = make_float4(u1.z, u1.w, u2.x, u2.y);
  ((float*) (wsb + B3_OFF))[r] = u2.z;
}

// tile_k: 400 blocks = NPART depth-parts x 100 tiles, 512 threads (8 waves).
// Block (p,t) handles sorted ranks [1024p, 1024p+1024) for tile t:
//   A: 2-chunk ballot compaction with fused LDS staging (order-preserving).
//   B: 8-way segment blend; per-64 batch loaded lane-parallel from LDS, then
//      v_readlane register broadcast per entry (zero LDS-pipe in inner loop).
//   C: in-block 8-partial combine -> per-part pixel partial {T,r,g,b} to global.
__global__ __launch_bounds__(512) void tile_k(const char* __restrict__ wsb,
                                              float4* __restrict__ pp)
{
  __shared__ float4 sb1[RANGE];        // gx,gy,ca,cb
  __shared__ float4 sb2[RANGE];        // cc,op,r,g
  __shared__ float  sb3[RANGE];        // b
  __shared__ int    wcnt[2][8];
  __shared__ float  pT[8][64], pR[8][64], pG[8][64], pB[8][64];
  const float4* S0 = (const float4*)(wsb + S0_OFF);
  const float4* B1 = (const float4*)(wsb + B1_OFF);
  const float4* B2 = (const float4*)(wsb + B2_OFF);
  const float*  B3 = (const float*) (wsb + B3_OFF);

  int tid = threadIdx.x;
  int wv = tid >> 6, lane = tid & 63;
  int part = blockIdx.x / 100;
  int tile = blockIdx.x % 100;
  int base = part * RANGE;
  int x0 = (tile % 10) * 8, y0 = (tile / 10) * 8;
  float bx0 = (float)x0, bx1 = (float)(x0+7);
  float by0 = (float)y0, by1 = (float)(y0+7);

  int scnt = 0;  // wave-uniform running total
  #pragma unroll
  for (int c = 0; c < RANGE/512; ++c) {
    int i = base + c*512 + tid;
    float4 v = S0[i];                       // gx, gy, rcx, rcy (sorted)
    bool hit = (v.z > 0.0f) &&
               (v.x + v.z >= bx0) && (v.x - v.z <= bx1) &&
               (v.y + v.w >= by0) && (v.y - v.w <= by1);
    unsigned long long m = __ballot(hit);
    int par = c & 1;
    if (lane == 0) wcnt[par][wv] = __popcll(m);
    __syncthreads();
    int pre = 0, tot = 0;
    #pragma unroll
    for (int w = 0; w < 8; ++w) {
      int cw = wcnt[par][w];
      pre += (w < wv) ? cw : 0;
      tot += cw;
    }
    if (hit) {
      int pos = scnt + pre + __popcll(m & ((1ull<<lane)-1ull));
      sb1[pos] = B1[i];
      sb2[pos] = B2[i];
      sb3[pos] = B3[i];
    }
    scnt += tot;
  }
  __syncthreads();
  int cnt = scnt;                           // <= RANGE by construction

  // blend: 8 segments x 64 lanes(=pixels)
  float px = (float)(x0 + (lane & 7));
  float py = (float)(y0 + (lane >> 3));
  int seg = (cnt + 7) >> 3;
  int s0i = wv*seg;
  int s1i = s0i + seg; if (s1i > cnt) s1i = cnt;
  float T = 1.0f, ar = 0.f, ag = 0.f, ab = 0.f;
  for (int eb = s0i; eb < s1i; eb += 64) {
    int nn = s1i - eb; if (nn > 64) nn = 64;
    // lane-parallel batch stage into registers (3 LDS reads per 64 entries)
    float4 q1 = (lane < nn) ? sb1[eb+lane] : make_float4(0.f,0.f,0.f,0.f);
    float4 q2 = (lane < nn) ? sb2[eb+lane] : make_float4(0.f,0.f,0.f,0.f);
    float  r3 = (lane < nn) ? sb3[eb+lane] : 0.f;
    for (int c16 = 0; c16 < nn && __ballot(T >= 1e-4f); c16 += 16) {
      int ce = c16 + 16; if (ce > nn) ce = nn;
      for (int e = c16; e < ce; ++e) {
        float gxe = rdlane(q1.x, e), gye = rdlane(q1.y, e);
        float cae = rdlane(q1.z, e), cbe = rdlane(q1.w, e);
        float cce = rdlane(q2.x, e), ope = rdlane(q2.y, e);
        float cre = rdlane(q2.z, e), cge = rdlane(q2.w, e);
        float cble = rdlane(r3, e);
        float dx = gxe - px, dy = gye - py;
        float power = -0.5f*(cae*dx*dx + cce*dy*dy) - cbe*dx*dy;
        float al = 0.0f;
        if (power <= 0.0f) {
          float av = fminf(0.99f, ope*__expf(power));
          if (av >= (1.0f/255.0f)) al = av;
        }
        float w = al*T;
        ar += w*cre; ag += w*cge; ab += w*cble;
        T *= 1.0f - al;
      }
    }
  }
  pT[wv][lane]=T; pR[wv][lane]=ar; pG[wv][lane]=ag; pB[wv][lane]=ab;
  __syncthreads();

  if (tid < 64) {
    float Tg = 1.0f, r = 0.f, g2 = 0.f, b2 = 0.f;
    #pragma unroll
    for (int w = 0; w < 8; ++w) {
      r  += Tg*pR[w][tid];
      g2 += Tg*pG[w][tid];
      b2 += Tg*pB[w][tid];
      Tg *= pT[w][tid];
    }
    int p = (y0 + (tid>>3))*WI + (x0 + (tid&7));
    pp[part*NPIX + p] = make_float4(Tg, r, g2, b2);
  }
}

// combine_k: fold NPART partials front-to-back per pixel, add bg.
__global__ __launch_bounds__(256) void combine_k(const float4* __restrict__ pp,
                                                 const float* __restrict__ bg,
                                                 float* __restrict__ out)
{
  int p = blockIdx.x*256 + threadIdx.x;
  float T = 1.0f, r = 0.f, g = 0.f, b = 0.f;
  #pragma unroll
  for (int part = 0; part < NPART; ++part) {
    float4 q = pp[part*NPIX + p];
    r += T*q.y; g += T*q.z; b += T*q.w;
    T *= q.x;
  }
  out[0*NPIX+p] = r + T*bg[0];
  out[1*NPIX+p] = g + T*bg[1];
  out[2*NPIX+p] = b + T*bg[2];
}

extern "C" void kernel_launch(void* const* d_in, const int* in_sizes, int n_in,
                              void* d_out, int out_size, void* d_ws, size_t ws_size,
                              hipStream_t stream) {
  const float* means  = (const float*)d_in[0];
  const float* sh     = (const float*)d_in[1];
  const int*   shidx  = (const int*)  d_in[2];
  const int*   gidx   = (const int*)  d_in[3];
  const float* opac   = (const float*)d_in[4];
  const float* scales = (const float*)d_in[5];
  const float* sfac   = (const float*)d_in[6];
  const float* rots   = (const float*)d_in[7];
  const float* ext    = (const float*)d_in[8];
  const float* bg     = (const float*)d_in[9];
  float* out = (float*)d_out;
  char* wsb = (char*)d_ws;
  float4* pp = (float4*)(wsb + PP_OFF);

  prep_k<<<NG/256, 256, 0, stream>>>(means, sh, shidx, gidx, opac, scales, sfac,
                                     rots, ext, wsb, out + 3*NPIX);
  dim3 rg(NG/256, NG/256);
  rank_k<<<rg, 256, 0, stream>>>(wsb, (int*)(wsb + RK_OFF));
  scatter_k<<<NG/256, 256, 0, stream>>>(wsb);
  tile_k<<<100*NPART, 512, 0, stream>>>(wsb, pp);
  combine_k<<<NPIX/256, 256, 0, stream>>>(pp, bg, out);
}